// Round 5
// baseline (211.696 us; speedup 1.0000x reference)
//
#include <hip/hip_runtime.h>

typedef unsigned int   u32;
typedef unsigned short u16;
typedef short bf16x8 __attribute__((ext_vector_type(8)));
typedef float f32x4  __attribute__((ext_vector_type(4)));

#define GAS(p) ((const __attribute__((address_space(1))) void*)(p))
#define LAS(p) ((__attribute__((address_space(3))) void*)(p))

__device__ __forceinline__ u16 f2bf(float f) {
  union { float f; u32 u; } v; v.f = f;
  u32 r = v.u + 0x7fffu + ((v.u >> 16) & 1u);
  return (u16)(r >> 16);
}
__device__ __forceinline__ u32 pack2(float a, float b) {
  return (u32)f2bf(a) | ((u32)f2bf(b) << 16);
}

// ---------------- unified f32 -> bf16 convert (all 5 inputs, 1 launch) -------
__global__ __launch_bounds__(256) void cvt_all(
    const float* __restrict__ q,  const float* __restrict__ wq,
    const float* __restrict__ wk, const float* __restrict__ wv,
    const float* __restrict__ wo, u16* __restrict__ xb,
    u16* __restrict__ wqkb, u16* __restrict__ wvb, u16* __restrict__ wob) {
  const int b = blockIdx.x;
  const float* src; u16* dst; long off;
  if (b < 2048)      { src = q;  dst = xb;             off = (long)b * 2048; }
  else if (b < 2560) { src = wq; dst = wqkb;           off = (long)(b - 2048) * 2048; }
  else if (b < 3072) { src = wk; dst = wqkb + 1048576; off = (long)(b - 2560) * 2048; }
  else if (b < 3584) { src = wv; dst = wvb;            off = (long)(b - 3072) * 2048; }
  else               { src = wo; dst = wob;            off = (long)(b - 3584) * 2048; }
  const long i = off + (long)threadIdx.x * 8;
  const float4* xp = (const float4*)(src + i);
  float4 a = xp[0], c = xp[1];
  uint4 o;
  o.x = pack2(a.x, a.y); o.y = pack2(a.z, a.w);
  o.z = pack2(c.x, c.y); o.w = pack2(c.z, c.w);
  *(uint4*)(dst + i) = o;
}

// ============ ring-3 pipelined bf16 GEMM: C = A @ Bt^T (+epilogue) ===========
// BMT x 128 tile, BK=64, 8 waves (512 thr). Ring of 3 K-tile LDS buffers:
// iteration kt computes from buf kt%3 while staging tile kt+2 into (kt+2)%3.
// Race-free: the staged buf's last reader was tile kt-1 (previous iteration,
// behind a barrier); boundary s_waitcnt vmcnt(L) + s_barrier collectively
// confirms tile kt+1 (each wave's own L in-flight loads are tile kt+2's).
// vmcnt never drained to 0 inside the loop (T3+T4). T5 setprio around MFMA.
// LDS XOR-swizzle via pre-swizzled global source + swizzled ds_read (G4, r21).
#define EPI_QK_SPLIT_BF16 0
#define EPI_BIAS_ROW_BF16 1
#define EPI_SCALE_F32     2
#define EPI_BIAS_COL_F32  3
#define EPI_RESHAPE_BF16  4

template <int EPI, int BMT>
__device__ __forceinline__
void gemm3_body(const u16* __restrict__ Ab, int lda,
                const u16* __restrict__ Bb, int ldb,
                void* __restrict__ Cv, void* __restrict__ Cv2, long coff, int ldc,
                const float* __restrict__ bias, const float* __restrict__ bias2,
                float scale, int kTiles, long tm, long tn, u16* lds) {
  constexpr int NT   = (BMT == 256) ? 4 : 2;       // n-frags per wave
  constexpr int WTN  = NT * 16;                    // wave n-span
  constexpr int AL   = BMT / 64;                   // A stage loads/thread (4|2)
  constexpr int ABUF = BMT * 64;                   // u16 offset of B within buf
  constexpr int BUFS = ABUF + 128 * 64;            // u16 per buf

  const int tid = threadIdx.x, lane = tid & 63, w = tid >> 6;
  const int wm = (BMT == 256) ? (w >> 1) : (w >> 2);
  const int wn = (BMT == 256) ? (w & 1) : (w & 3);
  const int rl = lane >> 3;          // row-in-stripe this lane stages
  const int sl = (lane & 7) ^ rl;    // pre-swizzled 16B-slot index
  const int fr = lane & 15, fq = lane >> 4;

  u16* p0 = lds;                 // compute buf (tile kt)
  u16* p1 = lds + BUFS;          // next tile
  u16* p2 = lds + 2 * BUFS;      // stage target (tile kt+2)

  const int arows = (BMT == 256) ? 32 : 16;  // A rows staged per wave

#define STAGE_A(dst, kt_)                                                       \
  { const int k0_ = (kt_) * 64;                                                 \
    _Pragma("unroll")                                                           \
    for (int i = 0; i < AL; ++i) {                                              \
      const u16* g = Ab + (tm + w * arows + i * 8 + rl) * (long)lda + k0_ + sl * 8; \
      __builtin_amdgcn_global_load_lds(GAS(g), LAS(dst + (w * arows + i * 8) * 64), 16, 0, 0); \
    } }
#define STAGE_B(dst, kt_)                                                       \
  { const int k0_ = (kt_) * 64;                                                 \
    _Pragma("unroll")                                                           \
    for (int i = 0; i < 2; ++i) {                                               \
      const u16* g = Bb + (tn + w * 16 + i * 8 + rl) * (long)ldb + k0_ + sl * 8; \
      __builtin_amdgcn_global_load_lds(GAS(g), LAS(dst + ABUF + (w * 16 + i * 8) * 64), 16, 0, 0); \
    } }

  f32x4 acc[4][NT] = {};

  // prologue: stage tiles 0,1 ; confirm tile 0 (leave tile 1's loads flying)
  STAGE_A(p0, 0); STAGE_B(p0, 0);
  STAGE_A(p1, 1); STAGE_B(p1, 1);
  if constexpr (BMT == 256) asm volatile("s_waitcnt vmcnt(6)" ::: "memory");
  else                      asm volatile("s_waitcnt vmcnt(4)" ::: "memory");
  asm volatile("s_barrier" ::: "memory");

  for (int kt = 0; kt < kTiles; ++kt) {
    const bool pre = (kt + 2 < kTiles);
    bf16x8 bfr[NT][2], af[2][2];
    // ---- phase 0: load all B-frags + A-half0, stage A(kt+2), 16 MFMA ----
#pragma unroll
    for (int ni = 0; ni < NT; ++ni)
#pragma unroll
      for (int ks = 0; ks < 2; ++ks) {
        int row = wn * WTN + ni * 16 + fr;
        int slot = (ks * 4 + fq) ^ (fr & 7);
        bfr[ni][ks] = *(const bf16x8*)(p0 + ABUF + row * 64 + slot * 8);
      }
#pragma unroll
    for (int mi = 0; mi < 2; ++mi)
#pragma unroll
      for (int ks = 0; ks < 2; ++ks) {
        int row = wm * 64 + mi * 16 + fr;
        int slot = (ks * 4 + fq) ^ (fr & 7);
        af[mi][ks] = *(const bf16x8*)(p0 + row * 64 + slot * 8);
      }
    if (pre) STAGE_A(p2, kt + 2);
    __builtin_amdgcn_s_setprio(1);
#pragma unroll
    for (int mi = 0; mi < 2; ++mi)
#pragma unroll
      for (int ni = 0; ni < NT; ++ni)
#pragma unroll
        for (int ks = 0; ks < 2; ++ks)
          acc[mi][ni] = __builtin_amdgcn_mfma_f32_16x16x32_bf16(af[mi][ks], bfr[ni][ks], acc[mi][ni], 0, 0, 0);
    __builtin_amdgcn_s_setprio(0);
    asm volatile("s_barrier" ::: "memory");
    // ---- phase 1: A-half1, stage B(kt+2), 16 MFMA, boundary vmcnt+barrier ----
#pragma unroll
    for (int mi = 0; mi < 2; ++mi)
#pragma unroll
      for (int ks = 0; ks < 2; ++ks) {
        int row = wm * 64 + 32 + mi * 16 + fr;
        int slot = (ks * 4 + fq) ^ (fr & 7);
        af[mi][ks] = *(const bf16x8*)(p0 + row * 64 + slot * 8);
      }
    if (pre) STAGE_B(p2, kt + 2);
    __builtin_amdgcn_s_setprio(1);
#pragma unroll
    for (int mi = 0; mi < 2; ++mi)
#pragma unroll
      for (int ni = 0; ni < NT; ++ni)
#pragma unroll
        for (int ks = 0; ks < 2; ++ks)
          acc[2 + mi][ni] = __builtin_amdgcn_mfma_f32_16x16x32_bf16(af[mi][ks], bfr[ni][ks], acc[2 + mi][ni], 0, 0, 0);
    __builtin_amdgcn_s_setprio(0);
    if (kt + 1 < kTiles) {
      if (pre) {  // tile kt+2's loads may stay in flight; confirm tile kt+1
        if constexpr (BMT == 256) asm volatile("s_waitcnt vmcnt(6)" ::: "memory");
        else                      asm volatile("s_waitcnt vmcnt(4)" ::: "memory");
      } else {
        asm volatile("s_waitcnt vmcnt(0)" ::: "memory");
      }
      asm volatile("s_barrier" ::: "memory");
    }
    u16* t = p0; p0 = p1; p1 = p2; p2 = t;  // rotate ring
  }
#undef STAGE_A
#undef STAGE_B

  // epilogue: C/D layout col=lane&15, row=(lane>>4)*4+reg (verified m89/m91)
  const int cr = (lane >> 4) * 4;
  const int cc = lane & 15;
#pragma unroll
  for (int mt = 0; mt < 4; ++mt) {
#pragma unroll
    for (int nt = 0; nt < NT; ++nt) {
#pragma unroll
      for (int r = 0; r < 4; ++r) {
        float v = acc[mt][nt][r];
        long gm = tm + wm * 64 + mt * 16 + cr + r;
        long gn = tn + wn * WTN + nt * 16 + cc;
        if constexpr (EPI == EPI_QK_SPLIT_BF16) {
          if (gn < 1024) ((u16*)Cv )[gm * (long)ldc + gn]        = f2bf(v + bias [gn]);
          else           ((u16*)Cv2)[gm * (long)ldc + gn - 1024] = f2bf(v + bias2[gn - 1024]);
        } else if constexpr (EPI == EPI_BIAS_ROW_BF16) {
          ((u16*)Cv)[gm * (long)ldc + gn] = f2bf(v + bias[gm]);
        } else if constexpr (EPI == EPI_SCALE_F32) {
          ((float*)Cv)[coff + gm * ldc + gn] = v * scale;
        } else if constexpr (EPI == EPI_BIAS_COL_F32) {
          ((float*)Cv)[gm * (long)ldc + gn] = v + bias[gn];
        } else {  // EPI_RESHAPE_BF16: attn_out [h,s,d]->[s,h*d] faithful reshape
          long rr  = (gn >> 6) * 128 + (gm >> 4);
          long cc2 = ((gm & 15) << 6) + (gn & 63);
          ((u16*)Cv)[coff + rr * 1024 + cc2] = f2bf(v);
        }
      }
    }
  }
}

// QKV: blocks 0..511 QK-proj (128^2 tiles), 512..767 V-proj. 768 = 3 full rounds.
__global__ __launch_bounds__(512, 2)
void k_qkv(const u16* __restrict__ Xb, const u16* __restrict__ Wqkb,
           const u16* __restrict__ Wvb, u16* __restrict__ Qb, u16* __restrict__ Kb,
           u16* __restrict__ Vtb, const float* __restrict__ bq,
           const float* __restrict__ bk, const float* __restrict__ bv) {
  __shared__ __align__(16) u16 lds[3 * (128 * 64 + 128 * 64)];  // 96 KiB
  const int b = blockIdx.x;
  const int swz = (b & 7) * 96 + (b >> 3);  // XCD-contiguous (768%8==0, bijective)
  if (swz < 512) {
    long tm = (long)(swz & 31) * 128, tn = (long)(swz >> 5) * 128;
    gemm3_body<EPI_QK_SPLIT_BF16, 128>(Xb, 1024, Wqkb, 1024, Qb, Kb, 0, 1024,
                                       bq, bk, 0.f, 16, tm, tn, lds);
  } else {
    const int vb = swz - 512;
    long tm = (long)(vb & 7) * 128, tn = (long)(vb >> 3) * 128;
    gemm3_body<EPI_BIAS_ROW_BF16, 128>(Wvb, 1024, Xb, 1024, Vtb, nullptr, 0, 4096,
                                       bv, nullptr, 0.f, 16, tm, tn, lds);
  }
}

template <int EPI, int BMT>
__global__ __launch_bounds__(512, 2)
void k_gemm3(const u16* __restrict__ A, long sAz, int lda,
             const u16* __restrict__ Bt, long sBz, int ldb,
             void* __restrict__ Cv, long sCz, int ldc,
             const float* __restrict__ bias, float scale, int kTiles) {
  __shared__ __align__(16) u16 lds[3 * (BMT * 64 + 128 * 64)];  // 144|96 KiB
  long tm = (long)blockIdx.x * BMT, tn = (long)blockIdx.y * 128;
  gemm3_body<EPI, BMT>(A + (long)blockIdx.z * sAz, lda,
                       Bt + (long)blockIdx.z * sBz, ldb,
                       Cv, nullptr, (long)blockIdx.z * sCz, ldc,
                       bias, nullptr, scale, kTiles, tm, tn, lds);
}

// ---------------- row softmax: f32 [4096][2048] -> bf16 weights ----------------
__global__ __launch_bounds__(256) void softmax_k(const float* __restrict__ S,
                                                 u16* __restrict__ W) {
  const long row = blockIdx.x;
  const float* src = S + row * 2048;
  u16* dst = W + row * 2048;
  const int t = threadIdx.x, lane = t & 63, wid = t >> 6;

  const float4* sp = (const float4*)(src + t * 8);
  float4 a = sp[0], b = sp[1];
  float m = fmaxf(fmaxf(fmaxf(a.x, a.y), fmaxf(a.z, a.w)),
                  fmaxf(fmaxf(b.x, b.y), fmaxf(b.z, b.w)));
#pragma unroll
  for (int o = 32; o > 0; o >>= 1) m = fmaxf(m, __shfl_xor(m, o));
  __shared__ float redm[4], reds[4];
  if (lane == 0) redm[wid] = m;
  __syncthreads();
  m = fmaxf(fmaxf(redm[0], redm[1]), fmaxf(redm[2], redm[3]));

  float e[8];
  e[0] = __expf(a.x - m); e[1] = __expf(a.y - m);
  e[2] = __expf(a.z - m); e[3] = __expf(a.w - m);
  e[4] = __expf(b.x - m); e[5] = __expf(b.y - m);
  e[6] = __expf(b.z - m); e[7] = __expf(b.w - m);
  float s = ((e[0] + e[1]) + (e[2] + e[3])) + ((e[4] + e[5]) + (e[6] + e[7]));
#pragma unroll
  for (int o = 32; o > 0; o >>= 1) s += __shfl_xor(s, o);
  if (lane == 0) reds[wid] = s;
  __syncthreads();
  s = (reds[0] + reds[1]) + (reds[2] + reds[3]);
  float inv = 1.0f / s;

  uint4 o4;
  o4.x = pack2(e[0] * inv, e[1] * inv);
  o4.y = pack2(e[2] * inv, e[3] * inv);
  o4.z = pack2(e[4] * inv, e[5] * inv);
  o4.w = pack2(e[6] * inv, e[7] * inv);
  *(uint4*)(dst + t * 8) = o4;
}

// ---------------- launch ----------------
extern "C" void kernel_launch(void* const* d_in, const int* in_sizes, int n_in,
                              void* d_out, int out_size, void* d_ws, size_t ws_size,
                              hipStream_t stream) {
  const float* query = (const float*)d_in[0];
  const float* Wq = (const float*)d_in[1];
  const float* bq = (const float*)d_in[2];
  const float* Wk = (const float*)d_in[3];
  const float* bk = (const float*)d_in[4];
  const float* Wv = (const float*)d_in[5];
  const float* bv = (const float*)d_in[6];
  const float* Wo = (const float*)d_in[7];
  const float* bo = (const float*)d_in[8];
  float* out = (float*)d_out;

  char* ws = (char*)d_ws;
  u16*   Xb   = (u16*)(ws);                  // query bf16 [4096][1024]
  u16*   Wqkb = (u16*)(ws + 8388608);        // [2048][1024]  rows 0-1023 Wq, 1024-2047 Wk
  u16*   Wvb  = (u16*)(ws + 12582912);
  u16*   Wob  = (u16*)(ws + 14680064);
  u16*   Qb   = (u16*)(ws + 16777216);       // [4096][1024]
  u16*   Kb   = (u16*)(ws + 25165824);       // [4096][1024]
  u16*   Vtb  = (u16*)(ws + 33554432);       // [1024][4096]  Vt[e][b*2048+s]
  u16*   Rb   = (u16*)(ws + 41943040);       // [2][2048][1024] reshaped attn
  float* Sc   = (float*)(ws + 50331648);     // [2][2048][2048] scores f32
  u16*   Wt   = (u16*)(ws + 83886080);       // [2][2048][2048] weights bf16

  // all f32->bf16 converts in one launch
  cvt_all<<<4096, 256, 0, stream>>>(query, Wq, Wk, Wv, Wo, Xb, Wqkb, Wvb, Wob);

  // [Q|K] = X@[Wq;Wk]^T + bias  AND  Vt = Wv@X^T + bv   (768 tiles = 3 rounds)
  k_qkv<<<768, 512, 0, stream>>>(Xb, Wqkb, Wvb, Qb, Kb, Vtb, bq, bk, bv);

  // scores = (Q@K^T)/128 per batch: 256x128 tiles -> 256 blocks = 1 round
  k_gemm3<EPI_SCALE_F32, 256><<<dim3(8, 16, 2), 512, 0, stream>>>(
      Qb, 2048L * 1024, 1024, Kb, 2048L * 1024, 1024,
      Sc, 2048L * 2048, 2048, nullptr, 1.0f / 128.0f, 16);
  // softmax rows -> bf16 weights
  softmax_k<<<4096, 256, 0, stream>>>(Sc, Wt);
  // AO = W@V per batch (K=2048), faithful-reshape epilogue: 128 blocks
  k_gemm3<EPI_RESHAPE_BF16, 256><<<dim3(8, 8, 2), 512, 0, stream>>>(
      Wt, 2048L * 2048, 2048, Vtb, 2048, 4096,
      Rb, 2048L * 1024, 1024, nullptr, 0.f, 32);
  // out = R@Wo^T + bo: 128^2 tiles -> 256 blocks = 1 round
  k_gemm3<EPI_BIAS_COL_F32, 128><<<dim3(32, 8, 1), 512, 0, stream>>>(
      Rb, 0, 1024, Wob, 0, 1024, out, 0, 1024, bo, 0.f, 16);
}